// Round 8
// baseline (113.181 us; speedup 1.0000x reference)
//
#include <hip/hip_runtime.h>

// QueryEncDec: 2 stacks x 128 layers of scalar GRU (H=in=1), T=256.
// 4 waves x 64 lanes; wave w lane j owns global layer 64w+j.
// Intra-wave handoff: single DPP wave_shr:1 whose OLD operand carries the
// lane-0 feed value (invalid lane 0 reads old, bound_ctrl=false) and whose
// SRC is the PRE-commit candidate hc (equal to committed h whenever the
// consumer is active) -- zero cndmasks on the inter-lane chain.
// Cross-wave handoff: LDS mailbox, batch 8: one ds_read_b64 + one __ballot
// per 8 steps; producer collects lane-63 h history via DPP wave_shl:1 and
// lanes 56..63 flush 8 tagged slots with one ds_write_b64 every 8 steps
// (at si==6, covering t = s-70..s-63). Consumers pre-spin once on slot 8
// (lag ~78 vs 70 needed); steady-state tag checks pass first try.
// Gate constants (log2e, 2.0) folded into weights; x-leg pre-sums keep the
// h-path join short. Math identical to R7 (one benign fp reassociation).

#define T_LEN 256
#define MBOX  320              // 0..255 data slots, 256..319 per-lane dump
typedef unsigned long long u64;
typedef unsigned int u32;

__device__ __forceinline__ float fexp2(float x) { return __builtin_amdgcn_exp2f(x); }
__device__ __forceinline__ float frcp(float x)  { return __builtin_amdgcn_rcpf(x); }

struct CellW {
    float wri, wrh, brc;   // r gate, pre-scaled by -log2(e)
    float wzi, wzh, bzc;   // z gate, pre-scaled by -log2(e)
    float wni, bni;        // n gate input half, pre-scaled by 2*log2(e)
    float wnh, bnh;        // n gate hidden half, pre-scaled by 2*log2(e)
};

__device__ __forceinline__ float cell_step(const CellW& c, float x, float h) {
    // x-leg pre-sums (x arrives last, via DPP)
    const float xr  = __builtin_fmaf(c.wri, x, c.brc);
    const float xz  = __builtin_fmaf(c.wzi, x, c.bzc);
    const float gin = __builtin_fmaf(c.wni, x, c.bni);
    const float ghn = __builtin_fmaf(c.wnh, h, c.bnh);
    const float er  = fexp2(__builtin_fmaf(c.wrh, h, xr));
    const float ez  = fexp2(__builtin_fmaf(c.wzh, h, xz));
    const float r   = frcp(1.0f + er);
    const float z   = frcp(1.0f + ez);
    const float en  = fexp2(__builtin_fmaf(r, ghn, gin));   // e^{2v}
    const float q   = frcp(1.0f + en);                      // n = 1-2q
    const float A   = __builtin_fmaf(z, h - 1.0f, 1.0f);
    const float B   = __builtin_fmaf(2.0f, z, -2.0f);
    return __builtin_fmaf(q, B, A);                         // (1-z)n + z h
}

template<bool LAST>
__device__ __forceinline__ float run_wave(
    const int j, const CellW& c,
    volatile u64* inbox, volatile u64* outbox,
    float* __restrict__ out, float* __restrict__ dumpG)
{
    float h = 0.0f;
    float hc_prev = 0.0f;       // last step's pre-commit candidate (handed via DPP)
    u32 coll = 0;               // collector: lane m holds lane-63 h(step s-(63-m))
    const int js = j & 7;

    // pre-spin: slot 8 (tag 9) is flushed at producer step 78 -> lag ~78,
    // 8 steps of slack over the 70 required. Wave 0 (X mailbox) passes now.
    {
        u64 v = inbox[8];
        while (__ballot((u32)(v >> 32) == 9u) != ~0ull) v = inbox[8];
    }

    for (int s0 = 0; s0 < 320; s0 += 8) {
        u32 bval = 0;
        if (s0 < T_LEN) {               // uniform; one ds_read_b64 per 8 steps
            const int slot = s0 + js;
            u64 v = inbox[slot];
            while (__ballot((u32)(v >> 32) == (u32)(slot + 1)) != ~0ull)
                v = inbox[slot];        // safety net; cold in steady state
            bval = (u32)v;
        }
        #pragma unroll
        for (int si = 0; si < 8; ++si) {
            const int s = s0 + si;
            // lane-0 feed value, broadcast (off the h-chain: bval is a batch old)
            const int xv = __builtin_amdgcn_readlane((int)bval, si);
            // merged handoff: lane j <- lane j-1's hc_prev; lane 0 <- xv (old)
            const int xm = __builtin_amdgcn_update_dpp(
                xv, __builtin_bit_cast(int, hc_prev),
                0x138 /*wave_shr:1*/, 0xF, 0xF, false);
            const float x = __builtin_bit_cast(float, xm);

            const float hc = cell_step(c, x, h);
            const int t = s - j;
            h = ((u32)t < (u32)T_LEN) ? hc : h;     // commit (prefix/tail mask)
            hc_prev = hc;

            // collector: shift history DOWN (lane m <- m+1), insert committed h
            const int cs = __builtin_amdgcn_update_dpp(
                0, (int)coll, 0x130 /*wave_shl:1*/, 0xF, 0xF, false);
            coll = (j == 63) ? __builtin_bit_cast(u32, h) : (u32)cs;

            if (si == 6) {              // compile-time; flush at s = 8b+6
                // lane m in 56..63 holds lane-63 h for t = s + m - 126
                const int  tm   = s + j - 126;
                const bool real = (j >= 56) & (tm >= 0);
                const int  widx = real ? tm : (T_LEN + j);   // dump: 256+j
                outbox[widx] = ((u64)(u32)(tm + 1) << 32) | (u64)coll;
                if (LAST) {             // dec_out: coalesced 8-float store
                    float* p = real ? (out + tm) : (dumpG + j);
                    *p = __builtin_bit_cast(float, coll);
                }
            }
        }
    }
    return h;
}

__global__ __launch_bounds__(256, 1) void gru_pipe8(
    const float* __restrict__ X,
    const float* __restrict__ enc_w_ih, const float* __restrict__ enc_w_hh,
    const float* __restrict__ enc_b_ih, const float* __restrict__ enc_b_hh,
    const float* __restrict__ dec_w_ih, const float* __restrict__ dec_w_hh,
    const float* __restrict__ dec_b_ih, const float* __restrict__ dec_b_hh,
    float* __restrict__ out, float* __restrict__ dumpG)
{
    const int tid = threadIdx.x;        // global layer 0..255
    const int w   = tid >> 6;           // wave 0..3
    const int j   = tid & 63;

    __shared__ u64 xsM[T_LEN];          // X as a pre-tagged mailbox
    __shared__ u64 box[4][MBOX];        // box[3] = wave-3 trash (uniform code path)

    xsM[tid] = ((u64)(u32)(tid + 1) << 32) |
               (u64)__builtin_bit_cast(u32, X[tid]);
    box[0][tid] = 0ull;                 // data slots 0..255 need tag=0
    box[1][tid] = 0ull;
    box[2][tid] = 0ull;
    box[3][tid] = 0ull;

    // per-layer params (torch gate order r,z,n), constants folded
    const int pl = tid & 127;
    const float* wip = (tid < 128) ? enc_w_ih : dec_w_ih;
    const float* whp = (tid < 128) ? enc_w_hh : dec_w_hh;
    const float* bip = (tid < 128) ? enc_b_ih : dec_b_ih;
    const float* bhp = (tid < 128) ? enc_b_hh : dec_b_hh;
    const float L2E = 1.44269504088896340736f;
    CellW c;
    c.wri = -L2E * wip[3 * pl + 0];
    c.wrh = -L2E * whp[3 * pl + 0];
    c.brc = -L2E * (bip[3 * pl + 0] + bhp[3 * pl + 0]);
    c.wzi = -L2E * wip[3 * pl + 1];
    c.wzh = -L2E * whp[3 * pl + 1];
    c.bzc = -L2E * (bip[3 * pl + 1] + bhp[3 * pl + 1]);
    c.wni = 2.0f * L2E * wip[3 * pl + 2];
    c.bni = 2.0f * L2E * bip[3 * pl + 2];
    c.wnh = 2.0f * L2E * whp[3 * pl + 2];
    c.bnh = 2.0f * L2E * bhp[3 * pl + 2];

    __syncthreads();                    // the only block barrier

    volatile u64* inbox  = (w == 0) ? xsM : box[w - 1];
    volatile u64* outbox = box[w];

    float h;
    if (w == 3) h = run_wave<true >(j, c, inbox, outbox, out, dumpG);
    else        h = run_wave<false>(j, c, inbox, outbox, out, dumpG);

    // dec_h: final hidden of decoder layers (global layers 128..255)
    if (w >= 2) out[T_LEN + 64 * (w - 2) + j] = h;
}

extern "C" void kernel_launch(void* const* d_in, const int* in_sizes, int n_in,
                              void* d_out, int out_size, void* d_ws, size_t ws_size,
                              hipStream_t stream) {
    const float* X        = (const float*)d_in[0];
    const float* enc_w_ih = (const float*)d_in[1];
    const float* enc_w_hh = (const float*)d_in[2];
    const float* enc_b_ih = (const float*)d_in[3];
    const float* enc_b_hh = (const float*)d_in[4];
    const float* dec_w_ih = (const float*)d_in[5];
    const float* dec_w_hh = (const float*)d_in[6];
    const float* dec_b_ih = (const float*)d_in[7];
    const float* dec_b_hh = (const float*)d_in[8];
    float* out = (float*)d_out;
    float* dumpG = (float*)d_ws;

    gru_pipe8<<<1, 256, 0, stream>>>(X,
                                     enc_w_ih, enc_w_hh, enc_b_ih, enc_b_hh,
                                     dec_w_ih, dec_w_hh, dec_b_ih, dec_b_hh,
                                     out, dumpG);
}